// Round 3
// baseline (223.994 us; speedup 1.0000x reference)
//
#include <hip/hip_runtime.h>
#include <math.h>

#define N_ROWS 32768
#define KCODES 1024
#define DIM 64
#define OUT_Q 1
#define OUT_PERP 2097153
#define OUT_ENC 2097154
#define KSPLIT 16
#define CPW 64            // codes per chunk = KCODES/KSPLIT
#define GAP_QUANTA 64u    // flag threshold: 64 * 2^-21 ~ 3.05e-5 >> fp32 dot err

typedef float f32x2 __attribute__((ext_vector_type(2)));

__device__ __forceinline__ unsigned umin_(unsigned a, unsigned b) { return a < b ? a : b; }
__device__ __forceinline__ unsigned umax_(unsigned a, unsigned b) { return a > b ? a : b; }

// ---------------------------------------------------------------------------
// P0: sqnB21[k] = (0.25 + 0.5*||e_k||^2) * 2^21   (fp64 accumulate)
// dist packing: u = (uint)((0.5||e||^2 - x.e + 0.25) * 2^21); dist' in
// [0.91,1.09] mathematically -> u in [~0.16,0.34]*2^21 < 2^20, so (u<<10)|k
// fits 32 bits. Truncation is monotone; ties/near-ties land in the flagged
// band and get exact fp64 recheck.
// ---------------------------------------------------------------------------
__global__ void vq_sqnorm_kernel(const float* __restrict__ emb,
                                 float* __restrict__ sqnB21) {
    int k = blockIdx.x * blockDim.x + threadIdx.x;  // 1024 threads
    const float4* e4 = (const float4*)(emb + k * DIM);
    double s = 0.0;
#pragma unroll
    for (int q = 0; q < 16; ++q) {
        float4 v = e4[q];
        s += (double)v.x * v.x + (double)v.y * v.y +
             (double)v.z * v.z + (double)v.w * v.w;
    }
    sqnB21[k] = (float)((0.25 + 0.5 * s) * 2097152.0);
}

// ---------------------------------------------------------------------------
// A: argmin scan, LDS-broadcast codebook tile (DS ops are ordered ->
// pipelineable, unlike SMEM). Each lane owns one full x row in VGPRs; block
// = 4 waves x 64 rows = 256 rows, covers one 64-code chunk.
// Packed key: (fixedpoint(dist)<<10)|k; best/second via v_min/max_u32.
// Partials go to the encodings output region (overwritten later).
// ---------------------------------------------------------------------------
__global__ __launch_bounds__(256, 4) void vq_argmin_kernel(
    const float* __restrict__ x, const float* __restrict__ emb,
    const float* __restrict__ sqnB21, uint2* __restrict__ pairP) {
    __shared__ float4 elds[CPW * 16];  // 64 codes x 256B = 16 KB
    __shared__ float sqlds[CPW];
    int tid = threadIdx.x;
    int lane = tid & 63;
    int wave = tid >> 6;
    int c = blockIdx.x & (KSPLIT - 1);
    int rb = blockIdx.x >> 4;
    int k0 = c * CPW;

    // stage codebook chunk + packed sqnorms into LDS
    const float4* esrc = (const float4*)(emb + (size_t)k0 * DIM);
#pragma unroll
    for (int it = 0; it < 4; ++it) elds[it * 256 + tid] = esrc[it * 256 + tid];
    if (tid < CPW) sqlds[tid] = sqnB21[k0 + tid];

    // this lane's x row (stride-4096 loads, coalesced across lanes)
    int n = rb * 256 + wave * 64 + lane;
    const float* xp = x + ((n >> 12) * 262144 + (n & 4095));
    float xv[DIM];
#pragma unroll
    for (int d = 0; d < DIM; ++d) xv[d] = xp[d * 4096];
    __syncthreads();

    unsigned best = 0xFFFFFFFFu, second = 0xFFFFFFFFu;
    for (int kk = 0; kk < CPW; ++kk) {
        const float4* ew = &elds[kk * 16];
        float a0 = 0.f, a1 = 0.f, a2 = 0.f, a3 = 0.f;
#pragma unroll
        for (int q = 0; q < 16; ++q) {
            float4 ev = ew[q];  // uniform address -> LDS broadcast
            a0 = fmaf(ev.x, xv[4 * q + 0], a0);
            a1 = fmaf(ev.y, xv[4 * q + 1], a1);
            a2 = fmaf(ev.z, xv[4 * q + 2], a2);
            a3 = fmaf(ev.w, xv[4 * q + 3], a3);
        }
        float dot = (a0 + a1) + (a2 + a3);
        unsigned u = (unsigned)fmaf(dot, -2097152.0f, sqlds[kk]);
        unsigned p = (u << 10) | (unsigned)(k0 + kk);
        unsigned t = umax_(p, best);
        second = umin_(second, t);
        best = umin_(best, p);
    }
    pairP[c * N_ROWS + n] = make_uint2(best, second);
}

// ---------------------------------------------------------------------------
// M: merge the 16 chunk partials per row; write idx; flag near-ties.
// ---------------------------------------------------------------------------
__global__ void vq_merge_kernel(const uint2* __restrict__ pairP,
                                int* __restrict__ idxp,
                                int* __restrict__ flaglist,
                                int* __restrict__ flagcount) {
    int n = blockIdx.x * blockDim.x + threadIdx.x;  // 32768 threads
    uint2 p0 = pairP[n];
    unsigned b = p0.x, s = p0.y;
#pragma unroll
    for (int cc = 1; cc < KSPLIT; ++cc) {
        uint2 q = pairP[cc * N_ROWS + n];
        s = umin_(umin_(s, q.y), umax_(b, q.x));
        b = umin_(b, q.x);
    }
    idxp[n] = (int)(b & 1023u);
    if (((s >> 10) - (b >> 10)) < GAP_QUANTA) {
        int pos = atomicAdd(flagcount, 1);
        flaglist[pos] = n;
    }
}

// ---------------------------------------------------------------------------
// B: exact fp64 re-scan of flagged rows (one wave per row).
// ---------------------------------------------------------------------------
__global__ __launch_bounds__(256) void vq_recheck_kernel(
    const float* __restrict__ x, const float* __restrict__ emb,
    const int* __restrict__ flaglist, const int* __restrict__ flagcount,
    int* __restrict__ idxp) {
    int lane = threadIdx.x & 63;
    int gw = (blockIdx.x * blockDim.x + threadIdx.x) >> 6;  // 0..1023
    int nf = flagcount[0];
    int dg = lane & 3, kg = lane >> 2;
    for (int i = gw; i < nf; i += 1024) {
        int n = flaglist[i];
        const float* xp = x + ((n >> 12) * 262144 + (n & 4095) + dg * 16 * 4096);
        double xd[16];
#pragma unroll
        for (int j = 0; j < 16; ++j) xd[j] = (double)xp[j * 4096];
        double best = 1e300;
        int bi = 0;
        for (int j = 0; j < 64; ++j) {
            int k = kg * 64 + j;
            const float4* e4 = (const float4*)(emb + k * DIM + dg * 16);
            double u = 0.0;
#pragma unroll
            for (int q = 0; q < 4; ++q) {
                float4 ev = e4[q];
                double e0 = ev.x, e1 = ev.y, e2 = ev.z, e3 = ev.w;
                u += e0 * (0.5 * e0 - xd[q * 4 + 0]);
                u += e1 * (0.5 * e1 - xd[q * 4 + 1]);
                u += e2 * (0.5 * e2 - xd[q * 4 + 2]);
                u += e3 * (0.5 * e3 - xd[q * 4 + 3]);
            }
            u += __shfl_xor(u, 1);
            u += __shfl_xor(u, 2);
            if (u < best) { best = u; bi = k; }
        }
        for (int off = 4; off < 64; off <<= 1) {
            double ob = __shfl_down(best, off);
            int oi = __shfl_down(bi, off);
            if (ob < best) { best = ob; bi = oi; }
        }
        if (lane == 0) idxp[n] = bi;
    }
}

// ---------------------------------------------------------------------------
// C: gather quantized (NCHW), loss, counts, one-hot encodings.
// grid 2048 x 256; block owns 16 rows. Nontemporal stores for the streamed
// 142 MB of output.
// ---------------------------------------------------------------------------
__global__ __launch_bounds__(256) void vq_outputs_kernel(
    const float* __restrict__ x, const float* __restrict__ emb,
    const int* __restrict__ idxp, float* __restrict__ out,
    int* __restrict__ counts, double* __restrict__ losss) {
    int tid = threadIdx.x;
    int bi = blockIdx.x;
    // ---- phase 1: quantized + loss + counts (16 rows x 16 d-groups)
    int r = tid & 15;
    int dg = tid >> 4;
    int n = bi * 16 + r;
    int ix = idxp[n];
    int xoff = (n >> 12) * 262144 + (n & 4095);
    float4 ev = *(const float4*)(emb + ix * DIM + dg * 4);
    float* qp = out + OUT_Q + xoff;
    float lsum = 0.f;
#pragma unroll
    for (int j = 0; j < 4; ++j) {
        int d = dg * 4 + j;
        float e = (&ev.x)[j];
        float xval = x[xoff + d * 4096];
        float df = e - xval;
        lsum += df * df;
        __builtin_nontemporal_store(e, qp + d * 4096);
    }
    if (dg == 0) atomicAdd(&counts[ix], 1);
    double ls = (double)lsum;
    for (int off = 32; off > 0; off >>= 1) ls += __shfl_down(ls, off);
    __shared__ double red[4];
    if ((tid & 63) == 0) red[tid >> 6] = ls;
    __syncthreads();
    if (tid == 0) atomicAdd(losss, red[0] + red[1] + red[2] + red[3]);

    // ---- phase 2: one-hot rows (f32x2: enc base is 8B- but not 16B-aligned)
    float* enc = out + OUT_ENC;
    int r2 = tid >> 4;   // 0..15
    int cid = tid & 15;  // 16 threads per row
    int row = bi * 16 + r2;
    int iv = idxp[row];
    f32x2* erow = (f32x2*)(enc + (size_t)row * 1024);
#pragma unroll 4
    for (int i = 0; i < 32; ++i) {
        int c2 = cid + 16 * i;  // f32x2 index; lanes contiguous per instr
        f32x2 v;
        v.x = (2 * c2 == iv) ? 1.0f : 0.0f;
        v.y = (2 * c2 + 1 == iv) ? 1.0f : 0.0f;
        __builtin_nontemporal_store(v, erow + c2);
    }
}

// ---------------------------------------------------------------------------
// D: perplexity + loss scalars.
// ---------------------------------------------------------------------------
__global__ void vq_finalize_kernel(const int* __restrict__ counts,
                                   const double* __restrict__ losss,
                                   float* __restrict__ out) {
    __shared__ double red[1024];
    int t = threadIdx.x;
    double p = (double)counts[t] / 32768.0;
    red[t] = p * log(p + 1e-10);
    __syncthreads();
    for (int s = 512; s > 0; s >>= 1) {
        if (t < s) red[t] += red[t + s];
        __syncthreads();
    }
    if (t == 0) {
        out[OUT_PERP] = (float)exp(-red[0]);
        out[0] = (float)(losss[0] * (1.25 / 2097152.0));
    }
}

// ---------------------------------------------------------------------------
extern "C" void kernel_launch(void* const* d_in, const int* in_sizes, int n_in,
                              void* d_out, int out_size, void* d_ws,
                              size_t ws_size, hipStream_t stream) {
    (void)in_sizes; (void)n_in; (void)out_size; (void)ws_size;
    const float* x = (const float*)d_in[0];
    const float* emb = (const float*)d_in[1];
    float* out = (float*)d_out;
    char* p = (char*)d_ws;

    int* idxp = (int*)p;       p += 131072;
    int* flaglist = (int*)p;   p += 131072;
    float* sqnB21 = (float*)p; p += 4096;
    int* counts = (int*)p;     p += 4096;
    int* flagcount = (int*)p;  p += 8;  // 4 used + 4 pad
    double* losss = (double*)p;

    // argmin partials live in the encodings output region (fully overwritten
    // by vq_outputs_kernel afterwards): 16 * 32768 * 8 B = 4 MB << 128 MB.
    uint2* pairP = (uint2*)(out + OUT_ENC);

    (void)hipMemsetAsync(counts, 0, 4096 + 16, stream);

    vq_sqnorm_kernel<<<4, 256, 0, stream>>>(emb, sqnB21);
    vq_argmin_kernel<<<128 * KSPLIT, 256, 0, stream>>>(x, emb, sqnB21, pairP);
    vq_merge_kernel<<<128, 256, 0, stream>>>(pairP, idxp, flaglist, flagcount);
    vq_recheck_kernel<<<256, 256, 0, stream>>>(x, emb, flaglist, flagcount,
                                               idxp);
    vq_outputs_kernel<<<2048, 256, 0, stream>>>(x, emb, idxp, out, counts,
                                                losss);
    vq_finalize_kernel<<<1, 1024, 0, stream>>>(counts, losss, out);
}

// Round 4
// 193.009 us; speedup vs baseline: 1.1605x; 1.1605x over previous
//
#include <hip/hip_runtime.h>
#include <math.h>

#define N_ROWS 32768
#define KCODES 1024
#define DIM 64
#define OUT_Q 1
#define OUT_PERP 2097153
#define OUT_ENC 2097154
#define GAP_QUANTA 64u   // 64 * 2^-21 ~ 3.05e-5 >> bf16-split dot err (~1e-6)

using short8 = __attribute__((ext_vector_type(8))) short;   // 8 bf16 (4 VGPR)
using f32x4  = __attribute__((ext_vector_type(4))) float;
typedef float f32x2 __attribute__((ext_vector_type(2)));

__device__ __forceinline__ unsigned umin_(unsigned a, unsigned b){return a<b?a:b;}
__device__ __forceinline__ unsigned umax_(unsigned a, unsigned b){return a>b?a:b;}
// RTNE float->bf16
__device__ __forceinline__ unsigned short f2bf(float f){
    unsigned u = __float_as_uint(f);
    unsigned r = (u + 0x7FFFu + ((u >> 16) & 1u)) >> 16;
    return (unsigned short)r;
}
__device__ __forceinline__ float bf2f(unsigned short h){
    return __uint_as_float(((unsigned)h) << 16);
}

// ---------------------------------------------------------------------------
// P: per-code prep. sqnB21[k] = (0.25 + 0.5||e_k||^2)*2^21 (fp64), bf16 split
// of the codebook (eh + el), and zeroing of counts/flagcount/losss (replaces
// the mysterious 92us hipMemsetAsync dispatch).
// ---------------------------------------------------------------------------
__global__ void vq_prep_kernel(const float* __restrict__ emb,
                               float* __restrict__ sqnB21,
                               unsigned short* __restrict__ ebh,
                               unsigned short* __restrict__ ebl,
                               int* __restrict__ counts,
                               int* __restrict__ flagcount,
                               double* __restrict__ losss) {
    int k = blockIdx.x * 256 + threadIdx.x;  // 1024 threads
    counts[k] = 0;
    if (k == 0) { flagcount[0] = 0; losss[0] = 0.0; }
    const float4* e4 = (const float4*)(emb + k * DIM);
    unsigned* hp = (unsigned*)(ebh + k * DIM);
    unsigned* lp = (unsigned*)(ebl + k * DIM);
    double s = 0.0;
#pragma unroll
    for (int q = 0; q < 16; ++q) {
        float4 v = e4[q];
        unsigned short h0=f2bf(v.x), h1=f2bf(v.y), h2=f2bf(v.z), h3=f2bf(v.w);
        unsigned short l0=f2bf(v.x-bf2f(h0)), l1=f2bf(v.y-bf2f(h1)),
                       l2=f2bf(v.z-bf2f(h2)), l3=f2bf(v.w-bf2f(h3));
        hp[2*q]   = (unsigned)h0 | ((unsigned)h1 << 16);
        hp[2*q+1] = (unsigned)h2 | ((unsigned)h3 << 16);
        lp[2*q]   = (unsigned)l0 | ((unsigned)l1 << 16);
        lp[2*q+1] = (unsigned)l2 | ((unsigned)l3 << 16);
        s += (double)v.x*v.x + (double)v.y*v.y + (double)v.z*v.z + (double)v.w*v.w;
    }
    sqnB21[k] = (float)((0.25 + 0.5 * s) * 2097152.0);
}

// ---------------------------------------------------------------------------
// A: MFMA argmin. Block = 4 independent waves; wave owns 16 rows (A-frags in
// 16 VGPRs, built in-kernel from strided x + bf16 split) and scans all 1024
// codes in 16-wide N-tiles. 6 mfma_16x16x32_bf16 per tile (hh + hl + lh over
// two K=32 halves of D=64). C layout (m89): col=lane&15, row=(lane>>4)*4+reg.
// Packed key (fixed-point dist<<10 | code) tracked as best/second per row;
// cross-lane xor-reduce over the 16 code columns at the end. No LDS.
// ---------------------------------------------------------------------------
__global__ __launch_bounds__(256) void vq_argmin_mfma(
    const float* __restrict__ x, const unsigned short* __restrict__ ebh,
    const unsigned short* __restrict__ ebl, const float* __restrict__ sqnB21,
    uint2* __restrict__ pairP) {
    int lane = threadIdx.x & 63;
    int w = threadIdx.x >> 6;
    int col = lane & 15;       // A row for loads / C col (code) in epilogue
    int g = lane >> 4;         // k-group: frag holds k = g*8 + j
    int n = blockIdx.x * 64 + w * 16 + col;
    int xbase = (n >> 12) * 262144 + (n & 4095);

    short8 ah0, al0, ah1, al1;
#pragma unroll
    for (int j = 0; j < 8; ++j) {
        float v0 = x[xbase + (g * 8 + j) * 4096];
        unsigned short h0 = f2bf(v0);
        ah0[j] = (short)h0; al0[j] = (short)f2bf(v0 - bf2f(h0));
        float v1 = x[xbase + (32 + g * 8 + j) * 4096];
        unsigned short h1 = f2bf(v1);
        ah1[j] = (short)h1; al1[j] = (short)f2bf(v1 - bf2f(h1));
    }

    unsigned best[4] = {~0u, ~0u, ~0u, ~0u}, sec[4] = {~0u, ~0u, ~0u, ~0u};
    for (int c0 = 0; c0 < KCODES; c0 += 16) {
        int code = c0 + col;
        const short8* bhp = (const short8*)(ebh + code * 64 + g * 8);
        const short8* blp = (const short8*)(ebl + code * 64 + g * 8);
        short8 bh0 = bhp[0], bh1 = bhp[4];   // +4 short8 = +32 elems (d half 2)
        short8 bl0 = blp[0], bl1 = blp[4];
        float sqv = sqnB21[code];
        f32x4 a0 = {0.f, 0.f, 0.f, 0.f}, a1 = {0.f, 0.f, 0.f, 0.f};
        a0 = __builtin_amdgcn_mfma_f32_16x16x32_bf16(ah0, bh0, a0, 0, 0, 0);
        a0 = __builtin_amdgcn_mfma_f32_16x16x32_bf16(ah1, bh1, a0, 0, 0, 0);
        a1 = __builtin_amdgcn_mfma_f32_16x16x32_bf16(ah0, bl0, a1, 0, 0, 0);
        a1 = __builtin_amdgcn_mfma_f32_16x16x32_bf16(al0, bh0, a1, 0, 0, 0);
        a1 = __builtin_amdgcn_mfma_f32_16x16x32_bf16(ah1, bl1, a1, 0, 0, 0);
        a1 = __builtin_amdgcn_mfma_f32_16x16x32_bf16(al1, bh1, a1, 0, 0, 0);
#pragma unroll
        for (int r = 0; r < 4; ++r) {
            float s = a0[r] + a1[r];
            unsigned u = (unsigned)fmaf(s, -2097152.0f, sqv);
            unsigned pk = (u << 10) | (unsigned)code;
            unsigned t = umax_(pk, best[r]);
            sec[r] = umin_(sec[r], t);
            best[r] = umin_(best[r], pk);
        }
    }
    // reduce over the 16 code-columns (xor within 16-lane groups)
#pragma unroll
    for (int st = 1; st < 16; st <<= 1) {
#pragma unroll
        for (int r = 0; r < 4; ++r) {
            unsigned ob = __shfl_xor(best[r], st);
            unsigned os = __shfl_xor(sec[r], st);
            sec[r] = umin_(umin_(sec[r], os), umax_(best[r], ob));
            best[r] = umin_(best[r], ob);
        }
    }
    if (col == 0) {
        int rowbase = blockIdx.x * 64 + w * 16 + g * 4;
#pragma unroll
        for (int r = 0; r < 4; ++r)
            pairP[rowbase + r] = make_uint2(best[r], sec[r]);
    }
}

// ---------------------------------------------------------------------------
// F: extract idx, flag near-ties for exact recheck.
// ---------------------------------------------------------------------------
__global__ void vq_flag_kernel(const uint2* __restrict__ pairP,
                               int* __restrict__ idxp,
                               int* __restrict__ flaglist,
                               int* __restrict__ flagcount) {
    int n = blockIdx.x * blockDim.x + threadIdx.x;  // 32768 threads
    uint2 pr = pairP[n];
    idxp[n] = (int)(pr.x & 1023u);
    if (((pr.y >> 10) - (pr.x >> 10)) < GAP_QUANTA) {
        int pos = atomicAdd(flagcount, 1);
        flaglist[pos] = n;
    }
}

// ---------------------------------------------------------------------------
// B: exact fp64 re-scan of flagged rows (one wave per row).
// ---------------------------------------------------------------------------
__global__ __launch_bounds__(256) void vq_recheck_kernel(
    const float* __restrict__ x, const float* __restrict__ emb,
    const int* __restrict__ flaglist, const int* __restrict__ flagcount,
    int* __restrict__ idxp) {
    int lane = threadIdx.x & 63;
    int gw = (blockIdx.x * blockDim.x + threadIdx.x) >> 6;  // 0..1023
    int nf = flagcount[0];
    int dg = lane & 3, kg = lane >> 2;
    for (int i = gw; i < nf; i += 1024) {
        int n = flaglist[i];
        const float* xp = x + ((n >> 12) * 262144 + (n & 4095) + dg * 16 * 4096);
        double xd[16];
#pragma unroll
        for (int j = 0; j < 16; ++j) xd[j] = (double)xp[j * 4096];
        double best = 1e300;
        int bi = 0;
        for (int j = 0; j < 64; ++j) {
            int k = kg * 64 + j;
            const float4* e4 = (const float4*)(emb + k * DIM + dg * 16);
            double u = 0.0;
#pragma unroll
            for (int q = 0; q < 4; ++q) {
                float4 ev = e4[q];
                double e0 = ev.x, e1 = ev.y, e2 = ev.z, e3 = ev.w;
                u += e0 * (0.5 * e0 - xd[q * 4 + 0]);
                u += e1 * (0.5 * e1 - xd[q * 4 + 1]);
                u += e2 * (0.5 * e2 - xd[q * 4 + 2]);
                u += e3 * (0.5 * e3 - xd[q * 4 + 3]);
            }
            u += __shfl_xor(u, 1);
            u += __shfl_xor(u, 2);
            if (u < best) { best = u; bi = k; }
        }
        for (int off = 4; off < 64; off <<= 1) {
            double ob = __shfl_down(best, off);
            int oi = __shfl_down(bi, off);
            if (ob < best) { best = ob; bi = oi; }
        }
        if (lane == 0) idxp[n] = bi;
    }
}

// ---------------------------------------------------------------------------
// C: gather quantized (NCHW), loss, counts, one-hot encodings (NT stores).
// ---------------------------------------------------------------------------
__global__ __launch_bounds__(256) void vq_outputs_kernel(
    const float* __restrict__ x, const float* __restrict__ emb,
    const int* __restrict__ idxp, float* __restrict__ out,
    int* __restrict__ counts, double* __restrict__ losss) {
    int tid = threadIdx.x;
    int bi = blockIdx.x;
    int r = tid & 15;
    int dg = tid >> 4;
    int n = bi * 16 + r;
    int ix = idxp[n];
    int xoff = (n >> 12) * 262144 + (n & 4095);
    float4 ev = *(const float4*)(emb + ix * DIM + dg * 4);
    float* qp = out + OUT_Q + xoff;
    float lsum = 0.f;
#pragma unroll
    for (int j = 0; j < 4; ++j) {
        int d = dg * 4 + j;
        float e = (&ev.x)[j];
        float xval = x[xoff + d * 4096];
        float df = e - xval;
        lsum += df * df;
        __builtin_nontemporal_store(e, qp + d * 4096);
    }
    if (dg == 0) atomicAdd(&counts[ix], 1);
    double ls = (double)lsum;
    for (int off = 32; off > 0; off >>= 1) ls += __shfl_down(ls, off);
    __shared__ double red[4];
    if ((tid & 63) == 0) red[tid >> 6] = ls;
    __syncthreads();
    if (tid == 0) atomicAdd(losss, red[0] + red[1] + red[2] + red[3]);

    float* enc = out + OUT_ENC;
    int r2 = tid >> 4;
    int cid = tid & 15;
    int row = bi * 16 + r2;
    int iv = idxp[row];
    f32x2* erow = (f32x2*)(enc + (size_t)row * 1024);
#pragma unroll 4
    for (int i = 0; i < 32; ++i) {
        int c2 = cid + 16 * i;
        f32x2 v;
        v.x = (2 * c2 == iv) ? 1.0f : 0.0f;
        v.y = (2 * c2 + 1 == iv) ? 1.0f : 0.0f;
        __builtin_nontemporal_store(v, erow + c2);
    }
}

// ---------------------------------------------------------------------------
// D: perplexity + loss scalars.
// ---------------------------------------------------------------------------
__global__ void vq_finalize_kernel(const int* __restrict__ counts,
                                   const double* __restrict__ losss,
                                   float* __restrict__ out) {
    __shared__ double red[1024];
    int t = threadIdx.x;
    double p = (double)counts[t] / 32768.0;
    red[t] = p * log(p + 1e-10);
    __syncthreads();
    for (int s = 512; s > 0; s >>= 1) {
        if (t < s) red[t] += red[t + s];
        __syncthreads();
    }
    if (t == 0) {
        out[OUT_PERP] = (float)exp(-red[0]);
        out[0] = (float)(losss[0] * (1.25 / 2097152.0));
    }
}

// ---------------------------------------------------------------------------
extern "C" void kernel_launch(void* const* d_in, const int* in_sizes, int n_in,
                              void* d_out, int out_size, void* d_ws,
                              size_t ws_size, hipStream_t stream) {
    (void)in_sizes; (void)n_in; (void)out_size; (void)ws_size;
    const float* x = (const float*)d_in[0];
    const float* emb = (const float*)d_in[1];
    float* out = (float*)d_out;
    char* p = (char*)d_ws;

    int* idxp = (int*)p;       p += 131072;
    int* flaglist = (int*)p;   p += 131072;
    float* sqnB21 = (float*)p; p += 4096;
    int* counts = (int*)p;     p += 4096;
    int* flagcount = (int*)p;  p += 8;
    double* losss = (double*)p;

    // scratch in the encodings output region (fully overwritten by outputs):
    // enc+6 floats -> 16B-aligned. ebh/ebl: 128 KB each; pairP: 256 KB.
    float* enc = out + OUT_ENC;
    unsigned short* ebh = (unsigned short*)(enc + 6);
    unsigned short* ebl = ebh + KCODES * DIM;
    uint2* pairP = (uint2*)(ebl + KCODES * DIM);

    vq_prep_kernel<<<4, 256, 0, stream>>>(emb, sqnB21, ebh, ebl, counts,
                                          flagcount, losss);
    vq_argmin_mfma<<<512, 256, 0, stream>>>(x, ebh, ebl, sqnB21, pairP);
    vq_flag_kernel<<<128, 256, 0, stream>>>(pairP, idxp, flaglist, flagcount);
    vq_recheck_kernel<<<256, 256, 0, stream>>>(x, emb, flaglist, flagcount,
                                               idxp);
    vq_outputs_kernel<<<2048, 256, 0, stream>>>(x, emb, idxp, out, counts,
                                                losss);
    vq_finalize_kernel<<<1, 1024, 0, stream>>>(counts, losss, out);
}

// Round 5
// 165.456 us; speedup vs baseline: 1.3538x; 1.1665x over previous
//
#include <hip/hip_runtime.h>
#include <math.h>

#define N_ROWS 32768
#define KCODES 1024
#define DIM 64
#define OUT_Q 1
#define OUT_PERP 2097153
#define OUT_ENC 2097154
#define KSPLIT 4         // code chunks; wave scans KCODES/KSPLIT codes
#define CPCH 256         // codes per chunk
#define GAP_QUANTA 64u   // 64 * 2^-21 ~ 3.05e-5 >> bf16-split dot err (~1e-6)

using short8 = __attribute__((ext_vector_type(8))) short;   // 8 bf16 (4 VGPR)
using f32x4  = __attribute__((ext_vector_type(4))) float;
typedef float f32x2 __attribute__((ext_vector_type(2)));

__device__ __forceinline__ unsigned umin_(unsigned a, unsigned b){return a<b?a:b;}
__device__ __forceinline__ unsigned umax_(unsigned a, unsigned b){return a>b?a:b;}
// RTNE float->bf16
__device__ __forceinline__ unsigned short f2bf(float f){
    unsigned u = __float_as_uint(f);
    unsigned r = (u + 0x7FFFu + ((u >> 16) & 1u)) >> 16;
    return (unsigned short)r;
}
__device__ __forceinline__ float bf2f(unsigned short h){
    return __uint_as_float(((unsigned)h) << 16);
}

// ---------------------------------------------------------------------------
// P: per-code prep. sqnB21[k] = (0.25 + 0.5||e_k||^2)*2^21 (fp64), bf16 split
// of the codebook (eh + el), and zeroing of counts/flagcount/losss.
// ---------------------------------------------------------------------------
__global__ void vq_prep_kernel(const float* __restrict__ emb,
                               float* __restrict__ sqnB21,
                               unsigned short* __restrict__ ebh,
                               unsigned short* __restrict__ ebl,
                               int* __restrict__ counts,
                               int* __restrict__ flagcount,
                               double* __restrict__ losss) {
    int k = blockIdx.x * 256 + threadIdx.x;  // 1024 threads
    counts[k] = 0;
    if (k == 0) { flagcount[0] = 0; losss[0] = 0.0; }
    const float4* e4 = (const float4*)(emb + k * DIM);
    unsigned* hp = (unsigned*)(ebh + k * DIM);
    unsigned* lp = (unsigned*)(ebl + k * DIM);
    double s = 0.0;
#pragma unroll
    for (int q = 0; q < 16; ++q) {
        float4 v = e4[q];
        unsigned short h0=f2bf(v.x), h1=f2bf(v.y), h2=f2bf(v.z), h3=f2bf(v.w);
        unsigned short l0=f2bf(v.x-bf2f(h0)), l1=f2bf(v.y-bf2f(h1)),
                       l2=f2bf(v.z-bf2f(h2)), l3=f2bf(v.w-bf2f(h3));
        hp[2*q]   = (unsigned)h0 | ((unsigned)h1 << 16);
        hp[2*q+1] = (unsigned)h2 | ((unsigned)h3 << 16);
        lp[2*q]   = (unsigned)l0 | ((unsigned)l1 << 16);
        lp[2*q+1] = (unsigned)l2 | ((unsigned)l3 << 16);
        s += (double)v.x*v.x + (double)v.y*v.y + (double)v.z*v.z + (double)v.w*v.w;
    }
    sqnB21[k] = (float)((0.25 + 0.5 * s) * 2097152.0);
}

// ---------------------------------------------------------------------------
// A: MFMA argmin, 4-way K-split for occupancy (8192 waves = 8/SIMD).
// Wave owns 16 rows (A-frags from bf16-split x) and scans CPCH codes in
// 16-wide tiles: 6 mfma_16x16x32_bf16 per tile (hh + hl + lh over two K=32
// halves of D=64). C layout (m89): col=lane&15, row=(lane>>4)*4+reg.
// Packed key (fixed-point dist<<10 | code) tracked best/second per row.
// ---------------------------------------------------------------------------
__global__ __launch_bounds__(256) void vq_argmin_mfma(
    const float* __restrict__ x, const unsigned short* __restrict__ ebh,
    const unsigned short* __restrict__ ebl, const float* __restrict__ sqnB21,
    uint2* __restrict__ pairP) {
    int lane = threadIdx.x & 63;
    int w = threadIdx.x >> 6;
    int col = lane & 15;       // A row for loads / C col (code) in epilogue
    int g = lane >> 4;         // k-group: frag holds k = g*8 + j
    int rb = blockIdx.x >> 2;          // row-block 0..511
    int c = blockIdx.x & (KSPLIT - 1); // code chunk 0..3
    int n = rb * 64 + w * 16 + col;
    int xbase = (n >> 12) * 262144 + (n & 4095);

    short8 ah0, al0, ah1, al1;
#pragma unroll
    for (int j = 0; j < 8; ++j) {
        float v0 = x[xbase + (g * 8 + j) * 4096];
        unsigned short h0 = f2bf(v0);
        ah0[j] = (short)h0; al0[j] = (short)f2bf(v0 - bf2f(h0));
        float v1 = x[xbase + (32 + g * 8 + j) * 4096];
        unsigned short h1 = f2bf(v1);
        ah1[j] = (short)h1; al1[j] = (short)f2bf(v1 - bf2f(h1));
    }

    unsigned best[4] = {~0u, ~0u, ~0u, ~0u}, sec[4] = {~0u, ~0u, ~0u, ~0u};
    for (int c0 = c * CPCH; c0 < (c + 1) * CPCH; c0 += 16) {
        int code = c0 + col;
        const short8* bhp = (const short8*)(ebh + code * 64 + g * 8);
        const short8* blp = (const short8*)(ebl + code * 64 + g * 8);
        short8 bh0 = bhp[0], bh1 = bhp[4];   // +4 short8 = +32 elems (d half 2)
        short8 bl0 = blp[0], bl1 = blp[4];
        float sqv = sqnB21[code];
        f32x4 a0 = {0.f, 0.f, 0.f, 0.f}, a1 = {0.f, 0.f, 0.f, 0.f};
        a0 = __builtin_amdgcn_mfma_f32_16x16x32_bf16(ah0, bh0, a0, 0, 0, 0);
        a0 = __builtin_amdgcn_mfma_f32_16x16x32_bf16(ah1, bh1, a0, 0, 0, 0);
        a1 = __builtin_amdgcn_mfma_f32_16x16x32_bf16(ah0, bl0, a1, 0, 0, 0);
        a1 = __builtin_amdgcn_mfma_f32_16x16x32_bf16(al0, bh0, a1, 0, 0, 0);
        a1 = __builtin_amdgcn_mfma_f32_16x16x32_bf16(ah1, bl1, a1, 0, 0, 0);
        a1 = __builtin_amdgcn_mfma_f32_16x16x32_bf16(al1, bh1, a1, 0, 0, 0);
#pragma unroll
        for (int r = 0; r < 4; ++r) {
            float s = a0[r] + a1[r];
            unsigned u = (unsigned)fmaf(s, -2097152.0f, sqv);
            unsigned pk = (u << 10) | (unsigned)code;
            unsigned t = umax_(pk, best[r]);
            sec[r] = umin_(sec[r], t);
            best[r] = umin_(best[r], pk);
        }
    }
    // reduce over the 16 code-columns (xor within 16-lane groups)
#pragma unroll
    for (int st = 1; st < 16; st <<= 1) {
#pragma unroll
        for (int r = 0; r < 4; ++r) {
            unsigned ob = __shfl_xor(best[r], st);
            unsigned os = __shfl_xor(sec[r], st);
            sec[r] = umin_(umin_(sec[r], os), umax_(best[r], ob));
            best[r] = umin_(best[r], ob);
        }
    }
    if (col == 0) {
        int rowbase = rb * 64 + w * 16 + g * 4;
#pragma unroll
        for (int r = 0; r < 4; ++r)
            pairP[c * N_ROWS + rowbase + r] = make_uint2(best[r], sec[r]);
    }
}

// ---------------------------------------------------------------------------
// F: merge the 4 chunk partials per row; write idx; flag near-ties.
// ---------------------------------------------------------------------------
__global__ void vq_flag_kernel(const uint2* __restrict__ pairP,
                               int* __restrict__ idxp,
                               int* __restrict__ flaglist,
                               int* __restrict__ flagcount) {
    int n = blockIdx.x * blockDim.x + threadIdx.x;  // 32768 threads
    uint2 p0 = pairP[n];
    unsigned b = p0.x, s = p0.y;
#pragma unroll
    for (int cc = 1; cc < KSPLIT; ++cc) {
        uint2 q = pairP[cc * N_ROWS + n];
        s = umin_(umin_(s, q.y), umax_(b, q.x));
        b = umin_(b, q.x);
    }
    idxp[n] = (int)(b & 1023u);
    if (((s >> 10) - (b >> 10)) < GAP_QUANTA) {
        int pos = atomicAdd(flagcount, 1);
        flaglist[pos] = n;
    }
}

// ---------------------------------------------------------------------------
// B: exact fp64 re-scan of flagged rows (one wave per row).
// ---------------------------------------------------------------------------
__global__ __launch_bounds__(256) void vq_recheck_kernel(
    const float* __restrict__ x, const float* __restrict__ emb,
    const int* __restrict__ flaglist, const int* __restrict__ flagcount,
    int* __restrict__ idxp) {
    int lane = threadIdx.x & 63;
    int gw = (blockIdx.x * blockDim.x + threadIdx.x) >> 6;  // 0..1023
    int nf = flagcount[0];
    int dg = lane & 3, kg = lane >> 2;
    for (int i = gw; i < nf; i += 1024) {
        int n = flaglist[i];
        const float* xp = x + ((n >> 12) * 262144 + (n & 4095) + dg * 16 * 4096);
        double xd[16];
#pragma unroll
        for (int j = 0; j < 16; ++j) xd[j] = (double)xp[j * 4096];
        double best = 1e300;
        int bi = 0;
        for (int j = 0; j < 64; ++j) {
            int k = kg * 64 + j;
            const float4* e4 = (const float4*)(emb + k * DIM + dg * 16);
            double u = 0.0;
#pragma unroll
            for (int q = 0; q < 4; ++q) {
                float4 ev = e4[q];
                double e0 = ev.x, e1 = ev.y, e2 = ev.z, e3 = ev.w;
                u += e0 * (0.5 * e0 - xd[q * 4 + 0]);
                u += e1 * (0.5 * e1 - xd[q * 4 + 1]);
                u += e2 * (0.5 * e2 - xd[q * 4 + 2]);
                u += e3 * (0.5 * e3 - xd[q * 4 + 3]);
            }
            u += __shfl_xor(u, 1);
            u += __shfl_xor(u, 2);
            if (u < best) { best = u; bi = k; }
        }
        for (int off = 4; off < 64; off <<= 1) {
            double ob = __shfl_down(best, off);
            int oi = __shfl_down(bi, off);
            if (ob < best) { best = ob; bi = oi; }
        }
        if (lane == 0) idxp[n] = bi;
    }
}

// ---------------------------------------------------------------------------
// C: gather quantized (NCHW), loss, counts, one-hot encodings.
// Phase 1 (q/loss/counts): 16 rows x 16 d-groups, regular stores (L2 merges
// the 64B segments into full lines across adjacent blocks).
// Phase 2 (encodings): each WAVE sweeps whole rows -> every NT store is a
// 512B-contiguous run (64 lanes x f32x2). 4 rows/wave, 16 rows/block.
// ---------------------------------------------------------------------------
__global__ __launch_bounds__(256) void vq_outputs_kernel(
    const float* __restrict__ x, const float* __restrict__ emb,
    const int* __restrict__ idxp, float* __restrict__ out,
    int* __restrict__ counts, double* __restrict__ losss) {
    int tid = threadIdx.x;
    int bi = blockIdx.x;
    int r = tid & 15;
    int dg = tid >> 4;
    int n = bi * 16 + r;
    int ix = idxp[n];
    int xoff = (n >> 12) * 262144 + (n & 4095);
    float4 ev = *(const float4*)(emb + ix * DIM + dg * 4);
    float* qp = out + OUT_Q + xoff;
    float lsum = 0.f;
#pragma unroll
    for (int j = 0; j < 4; ++j) {
        int d = dg * 4 + j;
        float e = (&ev.x)[j];
        float xval = x[xoff + d * 4096];
        float df = e - xval;
        lsum += df * df;
        qp[d * 4096] = e;
    }
    if (dg == 0) atomicAdd(&counts[ix], 1);
    double ls = (double)lsum;
    for (int off = 32; off > 0; off >>= 1) ls += __shfl_down(ls, off);
    __shared__ double red[4];
    if ((tid & 63) == 0) red[tid >> 6] = ls;
    __syncthreads();
    if (tid == 0) atomicAdd(losss, red[0] + red[1] + red[2] + red[3]);

    // ---- phase 2: full-wave row sweeps, 512B contiguous NT stores
    float* enc = out + OUT_ENC;
    int lane = tid & 63;
    int w = tid >> 6;
    int lane2 = lane * 2;
#pragma unroll
    for (int i = 0; i < 4; ++i) {
        int row = bi * 16 + w * 4 + i;
        int iv = idxp[row];   // same address across wave -> L1 broadcast
        f32x2* erow = (f32x2*)(enc + (size_t)row * 1024);
#pragma unroll
        for (int j = 0; j < 8; ++j) {
            int c2 = lane2 + 128 * j;
            f32x2 v;
            v.x = (c2 == iv) ? 1.0f : 0.0f;
            v.y = (c2 + 1 == iv) ? 1.0f : 0.0f;
            __builtin_nontemporal_store(v, erow + lane + 64 * j);
        }
    }
}

// ---------------------------------------------------------------------------
// D: perplexity + loss scalars (wave-shuffle reduce, 2 barriers).
// ---------------------------------------------------------------------------
__global__ void vq_finalize_kernel(const int* __restrict__ counts,
                                   const double* __restrict__ losss,
                                   float* __restrict__ out) {
    __shared__ double red[16];
    int t = threadIdx.x;
    double p = (double)counts[t] / 32768.0;
    double v = p * log(p + 1e-10);
    for (int off = 32; off > 0; off >>= 1) v += __shfl_down(v, off);
    if ((t & 63) == 0) red[t >> 6] = v;
    __syncthreads();
    if (t == 0) {
        double s = 0.0;
#pragma unroll
        for (int i = 0; i < 16; ++i) s += red[i];
        out[OUT_PERP] = (float)exp(-s);
        out[0] = (float)(losss[0] * (1.25 / 2097152.0));
    }
}

// ---------------------------------------------------------------------------
extern "C" void kernel_launch(void* const* d_in, const int* in_sizes, int n_in,
                              void* d_out, int out_size, void* d_ws,
                              size_t ws_size, hipStream_t stream) {
    (void)in_sizes; (void)n_in; (void)out_size; (void)ws_size;
    const float* x = (const float*)d_in[0];
    const float* emb = (const float*)d_in[1];
    float* out = (float*)d_out;
    char* p = (char*)d_ws;

    int* idxp = (int*)p;       p += 131072;
    int* flaglist = (int*)p;   p += 131072;
    float* sqnB21 = (float*)p; p += 4096;
    int* counts = (int*)p;     p += 4096;
    int* flagcount = (int*)p;  p += 8;
    double* losss = (double*)p;

    // scratch in the encodings output region (fully overwritten by outputs):
    // enc+6 floats -> 16B-aligned. ebh/ebl: 128 KB each; pairP: 1 MB.
    float* enc = out + OUT_ENC;
    unsigned short* ebh = (unsigned short*)(enc + 6);
    unsigned short* ebl = ebh + KCODES * DIM;
    uint2* pairP = (uint2*)(ebl + KCODES * DIM);

    vq_prep_kernel<<<4, 256, 0, stream>>>(emb, sqnB21, ebh, ebl, counts,
                                          flagcount, losss);
    vq_argmin_mfma<<<512 * KSPLIT, 256, 0, stream>>>(x, ebh, ebl, sqnB21,
                                                     pairP);
    vq_flag_kernel<<<128, 256, 0, stream>>>(pairP, idxp, flaglist, flagcount);
    vq_recheck_kernel<<<256, 256, 0, stream>>>(x, emb, flaglist, flagcount,
                                               idxp);
    vq_outputs_kernel<<<2048, 256, 0, stream>>>(x, emb, idxp, out, counts,
                                                losss);
    vq_finalize_kernel<<<1, 1024, 0, stream>>>(counts, losss, out);
}